// Round 2
// baseline (1279.841 us; speedup 1.0000x reference)
//
#include <hip/hip_runtime.h>
#include <math.h>

// YIN pitch, MI355X. Constants from reference:
//   SR=16000, STRIDES=160, W=257, TAU_MAX=213, TAU_MIN=26, C=187, MEDIAN=30
#define T_LEN    160000
#define STRIDES  160
#define NF       1001
#define NB       64
#define W_LEN    257
#define TAU_MINC 26
#define C_LEN    187
#define NFRAMES  (NB * NF)     // 64064

// Per-wave LDS region: chunk-padded layout. slot(C) = C + (C>>3) spreads the
// stride-16-element (64B) access patterns across bank-quads while preserving
// 16B alignment of float4 chunks. Region = 296 chunk-slots = 1184 floats.
#define REG_F    1184
#define CM_BASE  320           // element base of cmnd array (chunk 80)

__device__ __forceinline__ int slotE(int E) {   // padded float index (E = element)
    int C = E >> 2;
    return ((C + (C >> 3)) << 2) | (E & 3);
}
__device__ __forceinline__ int slotC(int C) {   // padded float index of chunk start
    return (C + (C >> 3)) << 2;
}

__global__ __launch_bounds__(256, 4) void yin_frames(const float* __restrict__ in,
                                                     float* __restrict__ pitch) {
    __shared__ float R_[4][REG_F];

    const int wid  = threadIdx.x >> 6;
    const int lane = threadIdx.x & 63;
    const int frame = blockIdx.x * 4 + wid;
    const int b = frame / NF;
    const int f = frame - b * NF;
    float* R = R_[wid];

    // ---------------- phase 1: zero-fill pad region + stage frame ----------------
    // zero raw floats [288, 580)  (covers padded slots of elements 256..539)
    float4 z4; z4.x = 0.f; z4.y = 0.f; z4.z = 0.f; z4.w = 0.f;
    *(float4*)(R + 288 + 4 * lane) = z4;
    if (lane < 9) *(float4*)(R + 544 + 4 * lane) = z4;

    const float* src = in + (size_t)b * T_LEN;
    const int start = f * STRIDES;
    int e0 = start + 4 * lane;
    float4 q;
    if (e0 + 3 < T_LEN) {
        q = *(const float4*)(src + e0);
    } else {
        q.x = (e0 + 0 < T_LEN) ? src[e0 + 0] : 0.f;
        q.y = (e0 + 1 < T_LEN) ? src[e0 + 1] : 0.f;
        q.z = (e0 + 2 < T_LEN) ? src[e0 + 2] : 0.f;
        q.w = (e0 + 3 < T_LEN) ? src[e0 + 3] : 0.f;
    }
    *(float4*)(R + slotE(4 * lane)) = q;      // elements 4l..4l+3 (slots < 288)
    if (lane == 0) {
        int e2 = start + 256;
        R[slotE(256)] = (e2 < T_LEN) ? src[e2] : 0.f;
    }

    // ---------------- phase 2: cumsum of squares (wave scan, in regs) ----------------
    float p0 = q.x * q.x;
    float p1 = p0 + q.y * q.y;
    float p2 = p1 + q.z * q.z;
    float p3 = p2 + q.w * q.w;
    float sc = p3;
#pragma unroll
    for (int off = 1; off < 64; off <<= 1) {
        float o = __shfl_up(sc, off);
        if (lane >= off) sc += o;
    }
    float base = sc - p3;
    float4 csv;
    csv.x = base + p0; csv.y = base + p1; csv.z = base + p2; csv.w = base + p3;
    float s256 = R[slotE(256)];               // broadcast (same-wave write visible)
    float totE = __shfl(sc, 63) + s256 * s256;

    // ---------------- phase 3: autocorrelation, K-split 4 x 16-tau blocking ------
    // lane = (g,i): g = lane>>4 covers j in [64g,64g+64); i = lane&15 covers taus
    // 16i..16i+15. 20-float rolling register window, 1 strided + 1 semi-bcast
    // ds_read_b128 per 4-j step.
    const int g  = lane >> 4;
    const int ii = lane & 15;
    const int Ebase = (g << 6) + (ii << 4);   // 64g + 16i

    float acc[16];
#pragma unroll
    for (int k = 0; k < 16; ++k) acc[k] = 0.0f;

    float w[20];
#pragma unroll
    for (int k = 0; k < 5; ++k) {
        float4 t4 = *(const float4*)(R + slotE(Ebase + 4 * k));
        w[4 * k + 0] = t4.x; w[4 * k + 1] = t4.y; w[4 * k + 2] = t4.z; w[4 * k + 3] = t4.w;
    }
    float4 cq = *(const float4*)(R + slotE(g << 6));

#pragma unroll
    for (int t = 0; t < 16; ++t) {
        const float cc0 = cq.x, cc1 = cq.y, cc2 = cq.z, cc3 = cq.w;
        float4 nw, nc;
        if (t < 15) {   // prefetch next window quad + next c quad
            nw = *(const float4*)(R + slotE(Ebase + 4 * t + 20));
            nc = *(const float4*)(R + slotE((g << 6) + 4 * t + 4));
        }
#pragma unroll
        for (int tt = 0; tt < 16; ++tt) {
            acc[tt] = fmaf(cc0, w[(4 * t + 0 + tt) % 20], acc[tt]);
            acc[tt] = fmaf(cc1, w[(4 * t + 1 + tt) % 20], acc[tt]);
            acc[tt] = fmaf(cc2, w[(4 * t + 2 + tt) % 20], acc[tt]);
            acc[tt] = fmaf(cc3, w[(4 * t + 3 + tt) % 20], acc[tt]);
        }
        if (t < 15) {
            const int wb = (4 * t) % 20;      // quad just consumed as logical [0..3]
            w[wb + 0] = nw.x; w[wb + 1] = nw.y; w[wb + 2] = nw.z; w[wb + 3] = nw.w;
            cq = nc;
        }
    }

    // ---------------- phase 4: reduce partials over g (LDS round-trip) ----------
    // part[g][tau], chunk index = 66g + 4i + q  (stride 66 chunks keeps g spread
    // across bank-quads). Aliases the s region (s is dead now).
#pragma unroll
    for (int q4 = 0; q4 < 4; ++q4) {
        float4 v4;
        v4.x = acc[4 * q4 + 0]; v4.y = acc[4 * q4 + 1];
        v4.z = acc[4 * q4 + 2]; v4.w = acc[4 * q4 + 3];
        *(float4*)(R + slotC(g * 66 + ii * 4 + q4)) = v4;
    }
    float a0 = 0.f, a1 = 0.f, a2 = 0.f, a3 = 0.f;
#pragma unroll
    for (int gg = 0; gg < 4; ++gg) {
        float4 p4 = *(const float4*)(R + slotC(gg * 66 + lane));
        a0 += p4.x; a1 += p4.y; a2 += p4.z; a3 += p4.w;
    }
    // lane now owns corr[4l..4l+3]

    // ---------------- phase 5: CMND (old 4-tau/lane layout) ----------------------
    // cs[e] (inclusive cumsum of squares) written from regs; aliases part (dead).
    *(float4*)(R + slotE(4 * lane)) = csv;
    if (lane == 0) R[slotE(256)] = totE;
    float4 csr  = *(const float4*)(R + slotE(252 - 4 * lane));
    float csTop = R[slotE(256 - 4 * lane)];

    float d0 = csTop - 2.0f * a0 + totE - csv.x;
    float d1 = csr.w - 2.0f * a1 + totE - csv.y;
    float d2 = csr.z - 2.0f * a2 + totE - csv.z;
    float d3 = csr.y - 2.0f * a3 + totE - csv.w;
    if (lane == 0) d0 = 0.0f;                 // diff[0] excluded from prefix
    float l0 = d0, l1 = l0 + d1, l2 = l1 + d2, l3 = l2 + d3;
    float scn = l3;
#pragma unroll
    for (int off = 1; off < 64; off <<= 1) {
        float o = __shfl_up(scn, off);
        if (lane >= off) scn += o;
    }
    float pb = scn - l3;
    const int t0 = 4 * lane;
    float cd0 = d0 * (float)(t0 + 0) / (pb + l0 + 1e-7f);
    float cd1 = d1 * (float)(t0 + 1) / (pb + l1 + 1e-7f);
    float cd2 = d2 * (float)(t0 + 2) / (pb + l2 + 1e-7f);
    float cd3 = d3 * (float)(t0 + 3) / (pb + l3 + 1e-7f);
    if (lane <= 53) {                          // taus 0..215 (>=213 junk, never read)
        float4 cdv;
        cdv.x = (lane == 0) ? 1.0f : cd0;
        cdv.y = cd1; cdv.z = cd2; cdv.w = cd3;
        *(float4*)(R + slotE(CM_BASE + t0)) = cdv;
    }

    // ---------------- phase 6: threshold + tau searches via ballot ---------------
    // cmnd[i] = cm[TAU_MINC + i] = R[CM_BASE + 26 + i], i in [0,187)
    float am[3], bm[3], cm3[3];
#pragma unroll
    for (int r = 0; r < 3; ++r) {
        int i = r * 64 + lane;
        am[r]  = R[slotE(CM_BASE + 25 + i)];   // cmnd[i-1] (junk @ i=0, masked)
        bm[r]  = R[slotE(CM_BASE + 26 + i)];   // cmnd[i]
        cm3[r] = R[slotE(CM_BASE + 27 + i)];   // cmnd[i+1] (junk @ i=186, masked)
    }
    unsigned long long tm0 = __ballot((lane < 187)     && (bm[0] < 0.1f));
    unsigned long long tm1 = __ballot((64 + lane < 187) && (bm[1] < 0.1f));
    unsigned long long tm2 = __ballot((128 + lane < 187) && (bm[2] < 0.1f));
    int cand = tm0 ? (__ffsll(tm0) - 1)
             : (tm1 ? (64 + __ffsll(tm1) - 1)
             : (tm2 ? (128 + __ffsll(tm2) - 1) : 999));
    const int thold = (cand == 0 || cand == 999) ? C_LEN : cand;

    unsigned long long lm[3];
#pragma unroll
    for (int r = 0; r < 3; ++r) {
        int i = r * 64 + lane;
        bool left  = (i == 0)   || (bm[r] - am[r] <= 0.0f);
        bool right = (i == 186) || (cm3[r] - bm[r] >= 0.0f);
        lm[r] = __ballot((i >= thold) && (i < C_LEN) && left && right);
    }
    int tcand = lm[0] ? (__ffsll(lm[0]) - 1)
              : (lm[1] ? (64 + __ffsll(lm[1]) - 1)
              : (lm[2] ? (128 + __ffsll(lm[2]) - 1) : 999));
    const int tau = (tcand == 999) ? 0 : tcand;

    // ---------------- phase 7: parabolic interp + pitch --------------------------
    float pv = 0.0f;
    if (tau > 0) {
        float shift = 0.0f;
        if (tau <= C_LEN - 2) {
            float pp = R[slotE(CM_BASE + 26 + tau - 1)];
            float cc = R[slotE(CM_BASE + 26 + tau)];
            float nn = R[slotE(CM_BASE + 26 + tau + 1)];
            float aa = nn + pp - 2.0f * cc;
            float bb = 0.5f * (nn - pp);
            shift = (fabsf(bb) >= fabsf(aa)) ? 0.0f : (-bb / aa);
        }
        pv = 16000.0f / ((float)(tau + TAU_MINC + 1) + shift);
    }
    if (lane == 0) pitch[frame] = pv;
}

// 30-wide median (index 14 of ascending sort), edge-padded (15,14)
__global__ __launch_bounds__(256) void median_k(const float* __restrict__ pitch,
                                                float* __restrict__ out) {
    int idx = blockIdx.x * blockDim.x + threadIdx.x;
    if (idx >= NFRAMES) return;
    int b = idx / NF;
    int f = idx - b * NF;
    const float* p = pitch + b * NF;
    float v[30];
#pragma unroll
    for (int k = 0; k < 30; ++k) {
        int j = f + k - 15;
        j = (j < 0) ? 0 : ((j > NF - 1) ? NF - 1 : j);
        v[k] = p[j];
    }
    float result = 0.0f;
#pragma unroll 1
    for (int i = 0; i < 30; ++i) {
        int lt = 0, le = 0;
#pragma unroll
        for (int j = 0; j < 30; ++j) {
            lt += (v[j] < v[i]);
            le += (v[j] <= v[i]);
        }
        if (lt <= 14 && 14 < le) result = v[i];
    }
    out[idx] = result;
}

extern "C" void kernel_launch(void* const* d_in, const int* in_sizes, int n_in,
                              void* d_out, int out_size, void* d_ws, size_t ws_size,
                              hipStream_t stream) {
    (void)in_sizes; (void)n_in; (void)out_size; (void)ws_size;
    const float* in = (const float*)d_in[0];
    float* out = (float*)d_out;
    float* pitch = (float*)d_ws;     // NFRAMES floats = 256 KB scratch

    yin_frames<<<NFRAMES / 4, 256, 0, stream>>>(in, pitch);
    median_k<<<(NFRAMES + 255) / 256, 256, 0, stream>>>(pitch, out);
}